// Round 14
// baseline (415.641 us; speedup 1.0000x reference)
//
#include <hip/hip_runtime.h>

typedef __attribute__((ext_vector_type(8))) short bf16x8;
typedef __attribute__((ext_vector_type(4))) float f32x4;

__device__ __forceinline__ float b2f(ushort s) { return __uint_as_float(((uint)s) << 16); }
__device__ __forceinline__ ushort f2b(float f) {
  uint u = __float_as_uint(f);
  u += 0x7fff + ((u >> 16) & 1);   // RNE
  return (ushort)(u >> 16);
}

__device__ __forceinline__ void store_h(float* p, float v) { *p = v; }
__device__ __forceinline__ void store_h(ushort* p, float v) { *p = f2b(v); }

__device__ __forceinline__ float sigm_fast(float x) { return 1.f / (1.f + __expf(-x)); }
__device__ __forceinline__ float tanh_fast(float c) {
  float e = __expf(-2.f * fabsf(c));
  float t = (1.f - e) / (1.f + e);
  return copysignf(t, c);
}

// ---------------- transpose+cast: in (R x C) f32 -> out (C x R) bf16 ----------------
__global__ void transpose_kernel(const float* __restrict__ in, ushort* __restrict__ out,
                                 int R, int C) {
  __shared__ ushort tile[32][33];
  int bc = blockIdx.x << 5;
  int br = blockIdx.y << 5;
  int tx = threadIdx.x & 31;
  int ty = threadIdx.x >> 5;  // 0..7
#pragma unroll
  for (int i = 0; i < 32; i += 8)
    tile[ty + i][tx] = f2b(in[(size_t)(br + ty + i) * C + bc + tx]);
  __syncthreads();
#pragma unroll
  for (int i = 0; i < 32; i += 8)
    out[(size_t)(bc + ty + i) * R + br + tx] = tile[tx][ty + i];
}

// ---------------- embedding gather+cast ----------------
__global__ void embed_kernel(const int* __restrict__ tok, const float* __restrict__ emb,
                             ushort* __restrict__ x) {
  int tid = threadIdx.x;
  int r = (blockIdx.x << 2) + (tid >> 6);
  int c = (tid & 63) << 3;
  int t = tok[r];
  const float* src = emb + ((size_t)t << 9) + c;
  float4 a = *(const float4*)src;
  float4 b = *(const float4*)(src + 4);
  uint4 o;
  o.x = (uint)f2b(a.x) | ((uint)f2b(a.y) << 16);
  o.y = (uint)f2b(a.z) | ((uint)f2b(a.w) << 16);
  o.z = (uint)f2b(b.x) | ((uint)f2b(b.y) << 16);
  o.w = (uint)f2b(b.z) | ((uint)f2b(b.w) << 16);
  *(uint4*)(x + ((size_t)r << 9) + c) = o;
}

// ---------------- GEMM v5 (R10 best-measured: 110.8us, conflicts 0) -----------------
__global__ __launch_bounds__(512, 1) void gemm_bt5_kernel(
    const ushort* __restrict__ A, const ushort* __restrict__ BT,
    ushort* __restrict__ C, int M, int N, int K) {
  __shared__ char lds[2][65536];
  const int tid = threadIdx.x;
  const int lane = tid & 63;
  const int wave = tid >> 6;
  const int wr = wave >> 2;
  const int wc = wave & 3;

  const int xcd = blockIdx.x & 7;
  const int l = blockIdx.x >> 3;
  const int s = xcd * (gridDim.x >> 8) + (l >> 5);
  const int uu = l & 31;
  const int mt = ((s & 7) << 3) + (uu & 7);
  const int nt = ((s >> 3) << 2) + (uu >> 3);
  const int m0 = mt << 8;
  const int n0 = nt << 8;
  const int NT = K >> 6;

  const int k0s = ((lane >> 4) << 4) ^ ((lane & 7) << 4);
  const int aB0 = (wr << 14) + ((lane & 15) << 7) + k0s;
  const int aB1 = aB0 ^ 64;
  const int bB0 = 32768 + (wc << 13) + ((lane & 15) << 7) + k0s;
  const int bB1 = bB0 ^ 64;

  int srcoff[4];
#pragma unroll
  for (int sub = 0; sub < 4; ++sub) {
    int off = (sub << 13) + (tid << 4);
    int row = off >> 7;
    int col = ((off & 127) ^ ((row & 7) << 4)) >> 1;
    srcoff[sub] = row * K + col;
  }
  const ushort* Abase = A + (size_t)m0 * K;
  const ushort* Bbase = BT + (size_t)n0 * K;

  auto stage = [&](int t, int p) {
    const int tk = t << 6;
#pragma unroll
    for (int i = 0; i < 8; ++i) {
      int sub = i & 3;
      const ushort* src = ((i < 4) ? Abase : Bbase) + srcoff[sub] + tk;
      char* dst = lds[p] + ((i < 4) ? 0 : 32768) + (sub << 13) + (wave << 10);
      __builtin_amdgcn_global_load_lds(
          (const __attribute__((address_space(1))) void*)src,
          (__attribute__((address_space(3))) void*)dst, 16, 0, 0);
    }
  };

  f32x4 acc[8][4];
#pragma unroll
  for (int i = 0; i < 8; ++i)
#pragma unroll
    for (int j = 0; j < 4; ++j) acc[i][j] = (f32x4){0.f, 0.f, 0.f, 0.f};

  stage(0, 0);
  for (int t = 0; t < NT; ++t) {
    int p = t & 1;
    if (t + 1 < NT) {
      stage(t + 1, p ^ 1);
      asm volatile("s_waitcnt vmcnt(8)" ::: "memory");
    } else {
      asm volatile("s_waitcnt vmcnt(0)" ::: "memory");
    }
    __builtin_amdgcn_s_barrier();
    const char* base = (const char*)lds[0] + (p << 16);
    bf16x8 afA[8], bgA[4], afB[8], bgB[4];
#pragma unroll
    for (int mi = 0; mi < 8; ++mi) afA[mi] = *(const bf16x8*)(base + aB0 + (mi << 11));
#pragma unroll
    for (int ni = 0; ni < 4; ++ni) bgA[ni] = *(const bf16x8*)(base + bB0 + (ni << 11));
#pragma unroll
    for (int mi = 0; mi < 8; ++mi) afB[mi] = *(const bf16x8*)(base + aB1 + (mi << 11));
#pragma unroll
    for (int ni = 0; ni < 4; ++ni) bgB[ni] = *(const bf16x8*)(base + bB1 + (ni << 11));
    __builtin_amdgcn_s_setprio(1);
#pragma unroll
    for (int mi = 0; mi < 8; ++mi)
#pragma unroll
      for (int ni = 0; ni < 4; ++ni)
        acc[mi][ni] =
            __builtin_amdgcn_mfma_f32_16x16x32_bf16(afA[mi], bgA[ni], acc[mi][ni], 0, 0, 0);
#pragma unroll
    for (int mi = 0; mi < 8; ++mi)
#pragma unroll
      for (int ni = 0; ni < 4; ++ni)
        acc[mi][ni] =
            __builtin_amdgcn_mfma_f32_16x16x32_bf16(afB[mi], bgB[ni], acc[mi][ni], 0, 0, 0);
    __builtin_amdgcn_s_setprio(0);
    __builtin_amdgcn_s_barrier();
  }
#pragma unroll
  for (int mi = 0; mi < 8; ++mi) {
#pragma unroll
    for (int j = 0; j < 4; ++j) {
      int row = m0 + (wr << 7) + (mi << 4) + ((lane >> 4) << 2) + j;
      size_t bofs = (size_t)row * N + n0 + (wc << 6);
#pragma unroll
      for (int ni = 0; ni < 4; ++ni)
        C[bofs + (ni << 4) + (lane & 15)] = f2b(acc[mi][ni][j]);
    }
  }
}

// ---------------- SRU chunk-parallel bidirectional scan v2 ----------------
// R13 lesson (rule #15, inverted): __launch_bounds__(256,1) let the allocator target
// 1 wave/SIMD — same occupancy as the serial scan, so 8x more blocks bought nothing.
// v2: CL=16 (16 chunks/channel, stash 64 f32 regs, ~95 total) + __launch_bounds__(256,4)
// -> VGPR cap 128, 4 waves/SIMD resident. Same exact-replay two-pass math.
template <int KC, typename OT>
__global__ __launch_bounds__(256, 4) void sru_scan_chunked(
    const ushort* __restrict__ u, const float* __restrict__ bias,
    const ushort* __restrict__ xres, OT* __restrict__ hout, float* __restrict__ cout) {
  const int L = 256, CL = 16;
  __shared__ float Psh[256], Ssh[256];
  const int tid = threadIdx.x;
  const int j = tid >> 4;        // chunk 0..15
  const int chl = tid & 15;      // channel-local
  const int ch = blockIdx.x * 16 + chl;  // global channel
  const int h = ch & 511;
  const int dir = (ch >> 9) & 1;
  const float bfg = bias[dir * 512 + h];
  const float brg = bias[1024 + dir * 512 + h];
  const size_t ustep = (size_t)65536 * KC;
  const ushort* ubase = u + (size_t)ch * KC;
  const size_t hstep = 65536;
  const int t0 = dir ? (L - 1 - j * CL) : (j * CL);
  const int tstep = dir ? -1 : 1;

  float fv[CL], gv[CL], rv[CL], rx[CL];
  float c = 0.f, P = 1.f;
#pragma unroll
  for (int s = 0; s < CL; ++s) {
    int t = t0 + s * tstep;
    const ushort* up = ubase + (size_t)t * ustep;
    float xt, fg, rg, xr;
    if (KC == 4) {
      uint2 v = *(const uint2*)up;
      xt = b2f((ushort)(v.x & 0xffff));
      fg = b2f((ushort)(v.x >> 16));
      rg = b2f((ushort)(v.y & 0xffff));
      xr = b2f((ushort)(v.y >> 16));
    } else {
      xt = b2f(up[0]);
      fg = b2f(up[1]);
      rg = b2f(up[2]);
      xr = b2f(xres[ch + (size_t)t * hstep]);
    }
    float f = sigm_fast(fg + bfg);
    float r = sigm_fast(rg + brg);
    fv[s] = f;
    gv[s] = (1.f - f) * xt;
    rv[s] = r;
    rx[s] = (1.f - r) * xr;
    c = f * c + gv[s];
    P *= f;
  }
  Psh[(chl << 4) + j] = P;
  Ssh[(chl << 4) + j] = c;
  __syncthreads();
  float cin = 0.f;
#pragma unroll
  for (int k = 0; k < 15; ++k) {
    if (k < j) cin = Psh[(chl << 4) + k] * cin + Ssh[(chl << 4) + k];
  }
  c = cin;
#pragma unroll
  for (int s = 0; s < CL; ++s) {
    int t = t0 + s * tstep;
    c = fv[s] * c + gv[s];
    float hv = rv[s] * tanh_fast(c) + rx[s];
    store_h(hout + ch + (size_t)t * hstep, hv);
  }
  if (j == 15) cout[ch] = c;
}

// ---------------- dense_hidden ----------------
__global__ __launch_bounds__(512) void dense_kernel(
    const float* __restrict__ c12, const ushort* __restrict__ WdT,
    const float* __restrict__ bd, float* __restrict__ out) {
  int row = blockIdx.x;
  int j = threadIdx.x;
  const float* c = c12 + (size_t)row * 1024;
  float acc = bd[j];
#pragma unroll 8
  for (int k = 0; k < 1024; ++k) acc += c[k] * b2f(WdT[(size_t)k * 512 + j]);
  out[(size_t)row * 512 + j] = acc;
}

extern "C" void kernel_launch(void* const* d_in, const int* in_sizes, int n_in,
                              void* d_out, int out_size, void* d_ws, size_t ws_size,
                              hipStream_t stream) {
  const int* tok = (const int*)d_in[0];
  const float* emb = (const float*)d_in[1];
  const float* W0 = (const float*)d_in[2];
  const float* b0 = (const float*)d_in[3];
  const float* W1 = (const float*)d_in[4];
  const float* b1 = (const float*)d_in[5];
  const float* Wd = (const float*)d_in[6];
  const float* bd = (const float*)d_in[7];
  float* out = (float*)d_out;

  char* ws = (char*)d_ws;
  ushort* x = (ushort*)ws;                        //  16,777,216 B
  ushort* W0T = (ushort*)(ws + 16777216);         //   4,194,304 B
  ushort* W1T = (ushort*)(ws + 20971520);         //   6,291,456 B
  ushort* u = (ushort*)(ws + 27262976);           // 134,217,728 B (u0/u1 aliased)
  ushort* h1 = (ushort*)(ws + 161480704);         //  33,554,432 B
  float* c12 = (float*)(ws + 195035136);          //     524,288 B
  ushort* WdT = (ushort*)(ws + 27262976 + 100663296);  // dead tail of u after scan1

  transpose_kernel<<<dim3(128, 16), 256, 0, stream>>>(W0, W0T, 512, 4096);
  transpose_kernel<<<dim3(96, 32), 256, 0, stream>>>(W1, W1T, 1024, 3072);
  embed_kernel<<<4096, 256, 0, stream>>>(tok, emb, x);
  // u0 = x @ W0   (16384 x 4096)
  gemm_bt5_kernel<<<1024, 512, 0, stream>>>(x, W0T, u, 16384, 4096, 512);
  sru_scan_chunked<4, ushort><<<4096, 256, 0, stream>>>(u, b0, (const ushort*)nullptr, h1, c12);
  // u1 = h1 @ W1  (16384 x 3072)
  gemm_bt5_kernel<<<768, 512, 0, stream>>>(h1, W1T, u, 16384, 3072, 1024);
  sru_scan_chunked<3, float><<<4096, 256, 0, stream>>>(u, b1, h1, out, c12 + 65536);
  transpose_kernel<<<dim3(32, 16), 256, 0, stream>>>(Wd, WdT, 512, 1024);
  dense_kernel<<<128, 512, 0, stream>>>(c12, WdT, bd, out + 16777216);
}

// Round 15
// 406.180 us; speedup vs baseline: 1.0233x; 1.0233x over previous
//
#include <hip/hip_runtime.h>

typedef __attribute__((ext_vector_type(8))) short bf16x8;
typedef __attribute__((ext_vector_type(4))) float f32x4;

__device__ __forceinline__ float b2f(ushort s) { return __uint_as_float(((uint)s) << 16); }
__device__ __forceinline__ ushort f2b(float f) {
  uint u = __float_as_uint(f);
  u += 0x7fff + ((u >> 16) & 1);   // RNE
  return (ushort)(u >> 16);
}

__device__ __forceinline__ void store_h(float* p, float v) { *p = v; }
__device__ __forceinline__ void store_h(ushort* p, float v) { *p = f2b(v); }

__device__ __forceinline__ float sigm_fast(float x) { return 1.f / (1.f + __expf(-x)); }
__device__ __forceinline__ float tanh_fast(float c) {
  float e = __expf(-2.f * fabsf(c));
  float t = (1.f - e) / (1.f + e);
  return copysignf(t, c);
}

// ---------------- transpose+cast: in (R x C) f32 -> out (C x R) bf16 ----------------
__global__ void transpose_kernel(const float* __restrict__ in, ushort* __restrict__ out,
                                 int R, int C) {
  __shared__ ushort tile[32][33];
  int bc = blockIdx.x << 5;
  int br = blockIdx.y << 5;
  int tx = threadIdx.x & 31;
  int ty = threadIdx.x >> 5;  // 0..7
#pragma unroll
  for (int i = 0; i < 32; i += 8)
    tile[ty + i][tx] = f2b(in[(size_t)(br + ty + i) * C + bc + tx]);
  __syncthreads();
#pragma unroll
  for (int i = 0; i < 32; i += 8)
    out[(size_t)(bc + ty + i) * R + br + tx] = tile[tx][ty + i];
}

// ---------------- embedding gather+cast ----------------
__global__ void embed_kernel(const int* __restrict__ tok, const float* __restrict__ emb,
                             ushort* __restrict__ x) {
  int tid = threadIdx.x;
  int r = (blockIdx.x << 2) + (tid >> 6);
  int c = (tid & 63) << 3;
  int t = tok[r];
  const float* src = emb + ((size_t)t << 9) + c;
  float4 a = *(const float4*)src;
  float4 b = *(const float4*)(src + 4);
  uint4 o;
  o.x = (uint)f2b(a.x) | ((uint)f2b(a.y) << 16);
  o.y = (uint)f2b(a.z) | ((uint)f2b(a.w) << 16);
  o.z = (uint)f2b(b.x) | ((uint)f2b(b.y) << 16);
  o.w = (uint)f2b(b.z) | ((uint)f2b(b.w) << 16);
  *(uint4*)(x + ((size_t)r << 9) + c) = o;
}

// ---------------- GEMM v5 (R10 best-measured: 110.8us, conflicts 0) -----------------
__global__ __launch_bounds__(512, 1) void gemm_bt5_kernel(
    const ushort* __restrict__ A, const ushort* __restrict__ BT,
    ushort* __restrict__ C, int M, int N, int K) {
  __shared__ char lds[2][65536];
  const int tid = threadIdx.x;
  const int lane = tid & 63;
  const int wave = tid >> 6;
  const int wr = wave >> 2;
  const int wc = wave & 3;

  const int xcd = blockIdx.x & 7;
  const int l = blockIdx.x >> 3;
  const int s = xcd * (gridDim.x >> 8) + (l >> 5);
  const int uu = l & 31;
  const int mt = ((s & 7) << 3) + (uu & 7);
  const int nt = ((s >> 3) << 2) + (uu >> 3);
  const int m0 = mt << 8;
  const int n0 = nt << 8;
  const int NT = K >> 6;

  const int k0s = ((lane >> 4) << 4) ^ ((lane & 7) << 4);
  const int aB0 = (wr << 14) + ((lane & 15) << 7) + k0s;
  const int aB1 = aB0 ^ 64;
  const int bB0 = 32768 + (wc << 13) + ((lane & 15) << 7) + k0s;
  const int bB1 = bB0 ^ 64;

  int srcoff[4];
#pragma unroll
  for (int sub = 0; sub < 4; ++sub) {
    int off = (sub << 13) + (tid << 4);
    int row = off >> 7;
    int col = ((off & 127) ^ ((row & 7) << 4)) >> 1;
    srcoff[sub] = row * K + col;
  }
  const ushort* Abase = A + (size_t)m0 * K;
  const ushort* Bbase = BT + (size_t)n0 * K;

  auto stage = [&](int t, int p) {
    const int tk = t << 6;
#pragma unroll
    for (int i = 0; i < 8; ++i) {
      int sub = i & 3;
      const ushort* src = ((i < 4) ? Abase : Bbase) + srcoff[sub] + tk;
      char* dst = lds[p] + ((i < 4) ? 0 : 32768) + (sub << 13) + (wave << 10);
      __builtin_amdgcn_global_load_lds(
          (const __attribute__((address_space(1))) void*)src,
          (__attribute__((address_space(3))) void*)dst, 16, 0, 0);
    }
  };

  f32x4 acc[8][4];
#pragma unroll
  for (int i = 0; i < 8; ++i)
#pragma unroll
    for (int j = 0; j < 4; ++j) acc[i][j] = (f32x4){0.f, 0.f, 0.f, 0.f};

  stage(0, 0);
  for (int t = 0; t < NT; ++t) {
    int p = t & 1;
    if (t + 1 < NT) {
      stage(t + 1, p ^ 1);
      asm volatile("s_waitcnt vmcnt(8)" ::: "memory");
    } else {
      asm volatile("s_waitcnt vmcnt(0)" ::: "memory");
    }
    __builtin_amdgcn_s_barrier();
    const char* base = (const char*)lds[0] + (p << 16);
    bf16x8 afA[8], bgA[4], afB[8], bgB[4];
#pragma unroll
    for (int mi = 0; mi < 8; ++mi) afA[mi] = *(const bf16x8*)(base + aB0 + (mi << 11));
#pragma unroll
    for (int ni = 0; ni < 4; ++ni) bgA[ni] = *(const bf16x8*)(base + bB0 + (ni << 11));
#pragma unroll
    for (int mi = 0; mi < 8; ++mi) afB[mi] = *(const bf16x8*)(base + aB1 + (mi << 11));
#pragma unroll
    for (int ni = 0; ni < 4; ++ni) bgB[ni] = *(const bf16x8*)(base + bB1 + (ni << 11));
    __builtin_amdgcn_s_setprio(1);
#pragma unroll
    for (int mi = 0; mi < 8; ++mi)
#pragma unroll
      for (int ni = 0; ni < 4; ++ni)
        acc[mi][ni] =
            __builtin_amdgcn_mfma_f32_16x16x32_bf16(afA[mi], bgA[ni], acc[mi][ni], 0, 0, 0);
#pragma unroll
    for (int mi = 0; mi < 8; ++mi)
#pragma unroll
      for (int ni = 0; ni < 4; ++ni)
        acc[mi][ni] =
            __builtin_amdgcn_mfma_f32_16x16x32_bf16(afB[mi], bgB[ni], acc[mi][ni], 0, 0, 0);
    __builtin_amdgcn_s_setprio(0);
    __builtin_amdgcn_s_barrier();
  }
#pragma unroll
  for (int mi = 0; mi < 8; ++mi) {
#pragma unroll
    for (int j = 0; j < 4; ++j) {
      int row = m0 + (wr << 7) + (mi << 4) + ((lane >> 4) << 2) + j;
      size_t bofs = (size_t)row * N + n0 + (wc << 6);
#pragma unroll
      for (int ni = 0; ni < 4; ++ni)
        C[bofs + (ni << 4) + (lane & 15)] = f2b(acc[mi][ni][j]);
    }
  }
}

// ---------------- SRU chunk-parallel scan v3: named-scalar stash ----------------
// R14 lesson (rule #20): the 4x16 stash ARRAYS went to scratch despite static indices
// (written in one loop, read after a barrier) -> 180MB spill writes, 117us. v3 forces
// register allocation with 64 individually NAMED scalars via macro expansion.
// Demand ~95 regs < 128 cap (launch_bounds(256,4)) -> 4 waves/SIMD, no spill.
// Same exact-replay two-pass math as R13/R14 (both passed).
template <int KC, typename OT>
__global__ __launch_bounds__(256, 4) void sru_scan_chunked(
    const ushort* __restrict__ u, const float* __restrict__ bias,
    const ushort* __restrict__ xres, OT* __restrict__ hout, float* __restrict__ cout) {
  const int L = 256;
  __shared__ float Psh[256], Ssh[256];
  const int tid = threadIdx.x;
  const int j = tid >> 4;        // chunk 0..15 (16 steps each)
  const int chl = tid & 15;      // channel-local
  const int ch = blockIdx.x * 16 + chl;
  const int h = ch & 511;
  const int dir = (ch >> 9) & 1;
  const float bfg = bias[dir * 512 + h];
  const float brg = bias[1024 + dir * 512 + h];
  const size_t ustep = (size_t)65536 * KC;
  const ushort* ubase = u + (size_t)ch * KC;
  const size_t hstep = 65536;
  const int t0 = dir ? (L - 1 - j * 16) : (j * 16);
  const int tstep = dir ? -1 : 1;

#define SRU_DECL(s) float f_##s, g_##s, r_##s, x_##s;
  SRU_DECL(0) SRU_DECL(1) SRU_DECL(2) SRU_DECL(3)
  SRU_DECL(4) SRU_DECL(5) SRU_DECL(6) SRU_DECL(7)
  SRU_DECL(8) SRU_DECL(9) SRU_DECL(10) SRU_DECL(11)
  SRU_DECL(12) SRU_DECL(13) SRU_DECL(14) SRU_DECL(15)
#undef SRU_DECL

  float c = 0.f, P = 1.f;
#define SRU_LOAD(s)                                                    \
  {                                                                    \
    int t = t0 + (s) * tstep;                                          \
    const ushort* up = ubase + (size_t)t * ustep;                      \
    float xt, fg, rg, xr;                                              \
    if (KC == 4) {                                                     \
      uint2 v = *(const uint2*)up;                                     \
      xt = b2f((ushort)(v.x & 0xffff));                                \
      fg = b2f((ushort)(v.x >> 16));                                   \
      rg = b2f((ushort)(v.y & 0xffff));                                \
      xr = b2f((ushort)(v.y >> 16));                                   \
    } else {                                                           \
      xt = b2f(up[0]);                                                 \
      fg = b2f(up[1]);                                                 \
      rg = b2f(up[2]);                                                 \
      xr = b2f(xres[ch + (size_t)t * hstep]);                          \
    }                                                                  \
    float f = sigm_fast(fg + bfg);                                     \
    float r = sigm_fast(rg + brg);                                     \
    f_##s = f;                                                         \
    g_##s = (1.f - f) * xt;                                            \
    r_##s = r;                                                         \
    x_##s = (1.f - r) * xr;                                            \
    c = f * c + g_##s;                                                 \
    P *= f;                                                            \
  }
  SRU_LOAD(0) SRU_LOAD(1) SRU_LOAD(2) SRU_LOAD(3)
  SRU_LOAD(4) SRU_LOAD(5) SRU_LOAD(6) SRU_LOAD(7)
  SRU_LOAD(8) SRU_LOAD(9) SRU_LOAD(10) SRU_LOAD(11)
  SRU_LOAD(12) SRU_LOAD(13) SRU_LOAD(14) SRU_LOAD(15)
#undef SRU_LOAD

  Psh[(chl << 4) + j] = P;
  Ssh[(chl << 4) + j] = c;
  __syncthreads();
  float cin = 0.f;
#pragma unroll
  for (int k = 0; k < 15; ++k) {
    if (k < j) cin = Psh[(chl << 4) + k] * cin + Ssh[(chl << 4) + k];
  }
  c = cin;
#define SRU_OUT(s)                                                     \
  {                                                                    \
    c = f_##s * c + g_##s;                                             \
    float hv = r_##s * tanh_fast(c) + x_##s;                           \
    int t = t0 + (s) * tstep;                                          \
    store_h(hout + ch + (size_t)t * hstep, hv);                        \
  }
  SRU_OUT(0) SRU_OUT(1) SRU_OUT(2) SRU_OUT(3)
  SRU_OUT(4) SRU_OUT(5) SRU_OUT(6) SRU_OUT(7)
  SRU_OUT(8) SRU_OUT(9) SRU_OUT(10) SRU_OUT(11)
  SRU_OUT(12) SRU_OUT(13) SRU_OUT(14) SRU_OUT(15)
#undef SRU_OUT

  if (j == 15) cout[ch] = c;
}

// ---------------- dense_hidden ----------------
__global__ __launch_bounds__(512) void dense_kernel(
    const float* __restrict__ c12, const ushort* __restrict__ WdT,
    const float* __restrict__ bd, float* __restrict__ out) {
  int row = blockIdx.x;
  int j = threadIdx.x;
  const float* c = c12 + (size_t)row * 1024;
  float acc = bd[j];
#pragma unroll 8
  for (int k = 0; k < 1024; ++k) acc += c[k] * b2f(WdT[(size_t)k * 512 + j]);
  out[(size_t)row * 512 + j] = acc;
}

extern "C" void kernel_launch(void* const* d_in, const int* in_sizes, int n_in,
                              void* d_out, int out_size, void* d_ws, size_t ws_size,
                              hipStream_t stream) {
  const int* tok = (const int*)d_in[0];
  const float* emb = (const float*)d_in[1];
  const float* W0 = (const float*)d_in[2];
  const float* b0 = (const float*)d_in[3];
  const float* W1 = (const float*)d_in[4];
  const float* b1 = (const float*)d_in[5];
  const float* Wd = (const float*)d_in[6];
  const float* bd = (const float*)d_in[7];
  float* out = (float*)d_out;

  char* ws = (char*)d_ws;
  ushort* x = (ushort*)ws;                        //  16,777,216 B
  ushort* W0T = (ushort*)(ws + 16777216);         //   4,194,304 B
  ushort* W1T = (ushort*)(ws + 20971520);         //   6,291,456 B
  ushort* u = (ushort*)(ws + 27262976);           // 134,217,728 B (u0/u1 aliased)
  ushort* h1 = (ushort*)(ws + 161480704);         //  33,554,432 B
  float* c12 = (float*)(ws + 195035136);          //     524,288 B
  ushort* WdT = (ushort*)(ws + 27262976 + 100663296);  // dead tail of u after scan1

  transpose_kernel<<<dim3(128, 16), 256, 0, stream>>>(W0, W0T, 512, 4096);
  transpose_kernel<<<dim3(96, 32), 256, 0, stream>>>(W1, W1T, 1024, 3072);
  embed_kernel<<<4096, 256, 0, stream>>>(tok, emb, x);
  // u0 = x @ W0   (16384 x 4096)
  gemm_bt5_kernel<<<1024, 512, 0, stream>>>(x, W0T, u, 16384, 4096, 512);
  sru_scan_chunked<4, ushort><<<4096, 256, 0, stream>>>(u, b0, (const ushort*)nullptr, h1, c12);
  // u1 = h1 @ W1  (16384 x 3072)
  gemm_bt5_kernel<<<768, 512, 0, stream>>>(h1, W1T, u, 16384, 3072, 1024);
  sru_scan_chunked<3, float><<<4096, 256, 0, stream>>>(u, b1, h1, out, c12 + 65536);
  transpose_kernel<<<dim3(32, 16), 256, 0, stream>>>(Wd, WdT, 512, 1024);
  dense_kernel<<<128, 512, 0, stream>>>(c12, WdT, bd, out + 16777216);
}

// Round 16
// 391.120 us; speedup vs baseline: 1.0627x; 1.0385x over previous
//
#include <hip/hip_runtime.h>

typedef __attribute__((ext_vector_type(8))) short bf16x8;
typedef __attribute__((ext_vector_type(4))) float f32x4;

__device__ __forceinline__ float b2f(ushort s) { return __uint_as_float(((uint)s) << 16); }
__device__ __forceinline__ ushort f2b(float f) {
  uint u = __float_as_uint(f);
  u += 0x7fff + ((u >> 16) & 1);   // RNE
  return (ushort)(u >> 16);
}

__device__ __forceinline__ void store_h(float* p, float v) { *p = v; }
__device__ __forceinline__ void store_h(ushort* p, float v) { *p = f2b(v); }

__device__ __forceinline__ float sigm_fast(float x) { return 1.f / (1.f + __expf(-x)); }
__device__ __forceinline__ float tanh_fast(float c) {
  float e = __expf(-2.f * fabsf(c));
  float t = (1.f - e) / (1.f + e);
  return copysignf(t, c);
}

// ---------------- transpose+cast: in (R x C) f32 -> out (C x R) bf16 ----------------
__global__ void transpose_kernel(const float* __restrict__ in, ushort* __restrict__ out,
                                 int R, int C) {
  __shared__ ushort tile[32][33];
  int bc = blockIdx.x << 5;
  int br = blockIdx.y << 5;
  int tx = threadIdx.x & 31;
  int ty = threadIdx.x >> 5;  // 0..7
#pragma unroll
  for (int i = 0; i < 32; i += 8)
    tile[ty + i][tx] = f2b(in[(size_t)(br + ty + i) * C + bc + tx]);
  __syncthreads();
#pragma unroll
  for (int i = 0; i < 32; i += 8)
    out[(size_t)(bc + ty + i) * R + br + tx] = tile[tx][ty + i];
}

// ---------------- embedding gather+cast ----------------
__global__ void embed_kernel(const int* __restrict__ tok, const float* __restrict__ emb,
                             ushort* __restrict__ x) {
  int tid = threadIdx.x;
  int r = (blockIdx.x << 2) + (tid >> 6);
  int c = (tid & 63) << 3;
  int t = tok[r];
  const float* src = emb + ((size_t)t << 9) + c;
  float4 a = *(const float4*)src;
  float4 b = *(const float4*)(src + 4);
  uint4 o;
  o.x = (uint)f2b(a.x) | ((uint)f2b(a.y) << 16);
  o.y = (uint)f2b(a.z) | ((uint)f2b(a.w) << 16);
  o.z = (uint)f2b(b.x) | ((uint)f2b(b.y) << 16);
  o.w = (uint)f2b(b.z) | ((uint)f2b(b.w) << 16);
  *(uint4*)(x + ((size_t)r << 9) + c) = o;
}

// ---------------- GEMM v5 (R10 best-measured: 110.8us, conflicts 0) -----------------
__global__ __launch_bounds__(512, 1) void gemm_bt5_kernel(
    const ushort* __restrict__ A, const ushort* __restrict__ BT,
    ushort* __restrict__ C, int M, int N, int K) {
  __shared__ char lds[2][65536];
  const int tid = threadIdx.x;
  const int lane = tid & 63;
  const int wave = tid >> 6;
  const int wr = wave >> 2;
  const int wc = wave & 3;

  const int xcd = blockIdx.x & 7;
  const int l = blockIdx.x >> 3;
  const int s = xcd * (gridDim.x >> 8) + (l >> 5);
  const int uu = l & 31;
  const int mt = ((s & 7) << 3) + (uu & 7);
  const int nt = ((s >> 3) << 2) + (uu >> 3);
  const int m0 = mt << 8;
  const int n0 = nt << 8;
  const int NT = K >> 6;

  const int k0s = ((lane >> 4) << 4) ^ ((lane & 7) << 4);
  const int aB0 = (wr << 14) + ((lane & 15) << 7) + k0s;
  const int aB1 = aB0 ^ 64;
  const int bB0 = 32768 + (wc << 13) + ((lane & 15) << 7) + k0s;
  const int bB1 = bB0 ^ 64;

  int srcoff[4];
#pragma unroll
  for (int sub = 0; sub < 4; ++sub) {
    int off = (sub << 13) + (tid << 4);
    int row = off >> 7;
    int col = ((off & 127) ^ ((row & 7) << 4)) >> 1;
    srcoff[sub] = row * K + col;
  }
  const ushort* Abase = A + (size_t)m0 * K;
  const ushort* Bbase = BT + (size_t)n0 * K;

  auto stage = [&](int t, int p) {
    const int tk = t << 6;
#pragma unroll
    for (int i = 0; i < 8; ++i) {
      int sub = i & 3;
      const ushort* src = ((i < 4) ? Abase : Bbase) + srcoff[sub] + tk;
      char* dst = lds[p] + ((i < 4) ? 0 : 32768) + (sub << 13) + (wave << 10);
      __builtin_amdgcn_global_load_lds(
          (const __attribute__((address_space(1))) void*)src,
          (__attribute__((address_space(3))) void*)dst, 16, 0, 0);
    }
  };

  f32x4 acc[8][4];
#pragma unroll
  for (int i = 0; i < 8; ++i)
#pragma unroll
    for (int j = 0; j < 4; ++j) acc[i][j] = (f32x4){0.f, 0.f, 0.f, 0.f};

  stage(0, 0);
  for (int t = 0; t < NT; ++t) {
    int p = t & 1;
    if (t + 1 < NT) {
      stage(t + 1, p ^ 1);
      asm volatile("s_waitcnt vmcnt(8)" ::: "memory");
    } else {
      asm volatile("s_waitcnt vmcnt(0)" ::: "memory");
    }
    __builtin_amdgcn_s_barrier();
    const char* base = (const char*)lds[0] + (p << 16);
    bf16x8 afA[8], bgA[4], afB[8], bgB[4];
#pragma unroll
    for (int mi = 0; mi < 8; ++mi) afA[mi] = *(const bf16x8*)(base + aB0 + (mi << 11));
#pragma unroll
    for (int ni = 0; ni < 4; ++ni) bgA[ni] = *(const bf16x8*)(base + bB0 + (ni << 11));
#pragma unroll
    for (int mi = 0; mi < 8; ++mi) afB[mi] = *(const bf16x8*)(base + aB1 + (mi << 11));
#pragma unroll
    for (int ni = 0; ni < 4; ++ni) bgB[ni] = *(const bf16x8*)(base + bB1 + (ni << 11));
    __builtin_amdgcn_s_setprio(1);
#pragma unroll
    for (int mi = 0; mi < 8; ++mi)
#pragma unroll
      for (int ni = 0; ni < 4; ++ni)
        acc[mi][ni] =
            __builtin_amdgcn_mfma_f32_16x16x32_bf16(afA[mi], bgA[ni], acc[mi][ni], 0, 0, 0);
#pragma unroll
    for (int mi = 0; mi < 8; ++mi)
#pragma unroll
      for (int ni = 0; ni < 4; ++ni)
        acc[mi][ni] =
            __builtin_amdgcn_mfma_f32_16x16x32_bf16(afB[mi], bgB[ni], acc[mi][ni], 0, 0, 0);
    __builtin_amdgcn_s_setprio(0);
    __builtin_amdgcn_s_barrier();
  }
#pragma unroll
  for (int mi = 0; mi < 8; ++mi) {
#pragma unroll
    for (int j = 0; j < 4; ++j) {
      int row = m0 + (wr << 7) + (mi << 4) + ((lane >> 4) << 2) + j;
      size_t bofs = (size_t)row * N + n0 + (wc << 6);
#pragma unroll
      for (int ni = 0; ni < 4; ++ni)
        C[bofs + (ni << 4) + (lane & 15)] = f2b(acc[mi][ni][j]);
    }
  }
}

// ---------------- SRU chunk-parallel scan v4: raw-bf16 packed stash ----------------
// R14: f32 stash arrays -> scratch (180MB spill). R15: 64 named f32 scalars -> demand
// ~116-130 vs the 128 cap, still spilled. v4 stashes the RAW PACKED bf16 inputs: 2
// uint regs/step (KC=4: the loaded uint2 verbatim; KC=3: 2 manual packs). Pass 1
// computes only f (1 expf) for (P,S); pass 2 unpacks + recomputes f,r. Demand ~65-75
// regs << 128 cap (launch_bounds(256,4)) -> 4 waves/SIMD, no spill. Gate math on
// identical bf16 inputs = same numerics as the passing serial scan (~1e-7 assoc noise).
template <int KC, typename OT>
__global__ __launch_bounds__(256, 4) void sru_scan_chunked(
    const ushort* __restrict__ u, const float* __restrict__ bias,
    const ushort* __restrict__ xres, OT* __restrict__ hout, float* __restrict__ cout) {
  const int L = 256;
  __shared__ float Psh[256], Ssh[256];
  const int tid = threadIdx.x;
  const int j = tid >> 4;        // chunk 0..15 (16 steps each)
  const int chl = tid & 15;      // channel-local
  const int ch = blockIdx.x * 16 + chl;
  const int h = ch & 511;
  const int dir = (ch >> 9) & 1;
  const float bfg = bias[dir * 512 + h];
  const float brg = bias[1024 + dir * 512 + h];
  const size_t ustep = (size_t)65536 * KC;
  const ushort* ubase = u + (size_t)ch * KC;
  const size_t hstep = 65536;
  const int t0 = dir ? (L - 1 - j * 16) : (j * 16);
  const int tstep = dir ? -1 : 1;

#define SRU_DECL(s) uint w0_##s, w1_##s;
  SRU_DECL(0) SRU_DECL(1) SRU_DECL(2) SRU_DECL(3)
  SRU_DECL(4) SRU_DECL(5) SRU_DECL(6) SRU_DECL(7)
  SRU_DECL(8) SRU_DECL(9) SRU_DECL(10) SRU_DECL(11)
  SRU_DECL(12) SRU_DECL(13) SRU_DECL(14) SRU_DECL(15)
#undef SRU_DECL

  float c = 0.f, P = 1.f;
  // pass 1: stash raw inputs, compute f only, accumulate chunk summary (P, S=c)
#define SRU_LOAD(s)                                                    \
  {                                                                    \
    int t = t0 + (s) * tstep;                                          \
    const ushort* up = ubase + (size_t)t * ustep;                      \
    if (KC == 4) {                                                     \
      uint2 v = *(const uint2*)up;                                     \
      w0_##s = v.x;                                                    \
      w1_##s = v.y;                                                    \
    } else {                                                           \
      w0_##s = (uint)up[0] | ((uint)up[1] << 16);                      \
      w1_##s = (uint)up[2] | ((uint)xres[ch + (size_t)t * hstep] << 16); \
    }                                                                  \
    float xt = b2f((ushort)(w0_##s & 0xffff));                         \
    float f = sigm_fast(b2f((ushort)(w0_##s >> 16)) + bfg);            \
    c = f * c + (1.f - f) * xt;                                        \
    P *= f;                                                            \
  }
  SRU_LOAD(0) SRU_LOAD(1) SRU_LOAD(2) SRU_LOAD(3)
  SRU_LOAD(4) SRU_LOAD(5) SRU_LOAD(6) SRU_LOAD(7)
  SRU_LOAD(8) SRU_LOAD(9) SRU_LOAD(10) SRU_LOAD(11)
  SRU_LOAD(12) SRU_LOAD(13) SRU_LOAD(14) SRU_LOAD(15)
#undef SRU_LOAD

  Psh[(chl << 4) + j] = P;
  Ssh[(chl << 4) + j] = c;
  __syncthreads();
  float cin = 0.f;
#pragma unroll
  for (int k = 0; k < 15; ++k) {
    if (k < j) cin = Psh[(chl << 4) + k] * cin + Ssh[(chl << 4) + k];
  }
  c = cin;
  // pass 2: unpack, recompute gates, replay recurrence from exact entry state
#define SRU_OUT(s)                                                     \
  {                                                                    \
    float xt = b2f((ushort)(w0_##s & 0xffff));                         \
    float f = sigm_fast(b2f((ushort)(w0_##s >> 16)) + bfg);            \
    float r = sigm_fast(b2f((ushort)(w1_##s & 0xffff)) + brg);         \
    float xr = b2f((ushort)(w1_##s >> 16));                            \
    c = f * c + (1.f - f) * xt;                                        \
    float hv = r * tanh_fast(c) + (1.f - r) * xr;                      \
    int t = t0 + (s) * tstep;                                          \
    store_h(hout + ch + (size_t)t * hstep, hv);                        \
  }
  SRU_OUT(0) SRU_OUT(1) SRU_OUT(2) SRU_OUT(3)
  SRU_OUT(4) SRU_OUT(5) SRU_OUT(6) SRU_OUT(7)
  SRU_OUT(8) SRU_OUT(9) SRU_OUT(10) SRU_OUT(11)
  SRU_OUT(12) SRU_OUT(13) SRU_OUT(14) SRU_OUT(15)
#undef SRU_OUT

  if (j == 15) cout[ch] = c;
}

// ---------------- dense_hidden ----------------
__global__ __launch_bounds__(512) void dense_kernel(
    const float* __restrict__ c12, const ushort* __restrict__ WdT,
    const float* __restrict__ bd, float* __restrict__ out) {
  int row = blockIdx.x;
  int j = threadIdx.x;
  const float* c = c12 + (size_t)row * 1024;
  float acc = bd[j];
#pragma unroll 8
  for (int k = 0; k < 1024; ++k) acc += c[k] * b2f(WdT[(size_t)k * 512 + j]);
  out[(size_t)row * 512 + j] = acc;
}

extern "C" void kernel_launch(void* const* d_in, const int* in_sizes, int n_in,
                              void* d_out, int out_size, void* d_ws, size_t ws_size,
                              hipStream_t stream) {
  const int* tok = (const int*)d_in[0];
  const float* emb = (const float*)d_in[1];
  const float* W0 = (const float*)d_in[2];
  const float* b0 = (const float*)d_in[3];
  const float* W1 = (const float*)d_in[4];
  const float* b1 = (const float*)d_in[5];
  const float* Wd = (const float*)d_in[6];
  const float* bd = (const float*)d_in[7];
  float* out = (float*)d_out;

  char* ws = (char*)d_ws;
  ushort* x = (ushort*)ws;                        //  16,777,216 B
  ushort* W0T = (ushort*)(ws + 16777216);         //   4,194,304 B
  ushort* W1T = (ushort*)(ws + 20971520);         //   6,291,456 B
  ushort* u = (ushort*)(ws + 27262976);           // 134,217,728 B (u0/u1 aliased)
  ushort* h1 = (ushort*)(ws + 161480704);         //  33,554,432 B
  float* c12 = (float*)(ws + 195035136);          //     524,288 B
  ushort* WdT = (ushort*)(ws + 27262976 + 100663296);  // dead tail of u after scan1

  transpose_kernel<<<dim3(128, 16), 256, 0, stream>>>(W0, W0T, 512, 4096);
  transpose_kernel<<<dim3(96, 32), 256, 0, stream>>>(W1, W1T, 1024, 3072);
  embed_kernel<<<4096, 256, 0, stream>>>(tok, emb, x);
  // u0 = x @ W0   (16384 x 4096)
  gemm_bt5_kernel<<<1024, 512, 0, stream>>>(x, W0T, u, 16384, 4096, 512);
  sru_scan_chunked<4, ushort><<<4096, 256, 0, stream>>>(u, b0, (const ushort*)nullptr, h1, c12);
  // u1 = h1 @ W1  (16384 x 3072)
  gemm_bt5_kernel<<<768, 512, 0, stream>>>(h1, W1T, u, 16384, 3072, 1024);
  sru_scan_chunked<3, float><<<4096, 256, 0, stream>>>(u, b1, h1, out, c12 + 65536);
  transpose_kernel<<<dim3(32, 16), 256, 0, stream>>>(Wd, WdT, 512, 1024);
  dense_kernel<<<128, 512, 0, stream>>>(c12, WdT, bd, out + 16777216);
}